// Round 1
// 346.736 us; speedup vs baseline: 1.0191x; 1.0191x over previous
//
#include <hip/hip_runtime.h>

// BoxFilter (r=4): 9x9 clamped-window box SUM. Wave-streaming, float4/lane.
// Each wave: 62 active lanes x 4 cols = 248 input cols -> 240 output cols
// (1920 = 8 strips x 240). Streams SH=27 output rows (40 segments).
// Vertical 9-sum: register ring of float4 (static idx via 9-unrolled chunks).
// Horizontal 9-sum: per-lane prefix/suffix + 5 shuffles per 4 outputs:
//   h = suffix(own) + fullsum(lane+1) + prefix(lane+2).
//
// R1 change vs baseline: loads are STAGED per 9-row chunk into a dedicated
// st[9] buffer (36 extra VGPRs) that is batch-issued before any consumption.
// Baseline had VGPR_Count=40 == ring+vs exactly, so every load reused the
// ring slot WAR-freed one row earlier -> ~1 load in flight -> latency-bound
// (HBM 33%, VALUBusy 7%). Staging gives 9 loads in flight per wave.
// Output stores are non-temporal: output is never re-read, keep the input
// resident in the 256 MB LLC instead.
// Hard-coded B=8,C=3,H=1080,W=1920,r=4.

#define W_IMG 1920
#define H_IMG 1080
#define SH 27          // output rows per segment (1080 = 40*27, 27%9==0)
#define R 4

typedef float f4 __attribute__((ext_vector_type(4)));

__global__ void box9_wave4(const float* __restrict__ x,
                           float* __restrict__ out) {
    const int lane  = threadIdx.x & 63;
    const int wv    = threadIdx.x >> 6;
    const int strip = blockIdx.x * 4 + wv;     // 0..7
    const int seg   = blockIdx.y;              // 0..39
    const int img   = blockIdx.z;              // 0..23
    const long base = (long)img * (H_IMG * W_IMG);

    // Lane l covers input cols cin_raw..cin_raw+3 (lane 0 = left halo).
    const int  cin_raw = strip * 240 - 4 + 4 * lane;
    const int  cin     = min(max(cin_raw, 0), W_IMG - 4);  // clamped (valid addr)
    const bool colOK   = (cin_raw >= 0) && (cin_raw + 3 < W_IMG);
    const int  cout    = strip * 240 + 4 * lane;
    const bool stOK    = (lane < 60);

    const int row0 = seg * SH;
    const float* pcol = x + base + cin;        // + row*W_IMG added per row
    float* po = out + base + (long)row0 * W_IMG + cout;

    f4 ring[9];
    f4 vs = {0.f, 0.f, 0.f, 0.f};
    f4 st[9];                                  // load staging (breaks WAR on ring)

    // Prologue: batch-issue input rows row0-4 .. row0+3 (lower clamp only).
#pragma unroll
    for (int t = 0; t < 8; ++t) {
        const int row = row0 - R + t;
        const int rc  = max(row, 0);
        st[t] = *(const f4*)(pcol + (long)rc * W_IMG);
    }
#pragma unroll
    for (int t = 0; t < 8; ++t) {
        const int row = row0 - R + t;
        f4 v = st[t];
        if (row < 0 || !colOK) { v.x = 0.f; v.y = 0.f; v.z = 0.f; v.w = 0.f; }
        ring[t] = v;
        vs.x += v.x; vs.y += v.y; vs.z += v.z; vs.w += v.w;
    }

    // Main: 3 chunks of 9 (ring indices compile-time constant).
    for (int chunk = 0; chunk < SH; chunk += 9) {
        // Phase 1: batch-issue all 9 incoming-row loads for this chunk.
#pragma unroll
        for (int j = 0; j < 9; ++j) {
            const int row = row0 + chunk + j + R;   // incoming input row
            const int rc  = min(row, H_IMG - 1);    // upper clamp only
            st[j] = *(const f4*)(pcol + (long)rc * W_IMG);
        }
        // Phase 2: consume, slide window, horizontal sum, store.
#pragma unroll
        for (int j = 0; j < 9; ++j) {
            const int row = row0 + chunk + j + R;
            f4 v = st[j];
            if (row >= H_IMG || !colOK) { v.x = 0.f; v.y = 0.f; v.z = 0.f; v.w = 0.f; }
            vs.x += v.x; vs.y += v.y; vs.z += v.z; vs.w += v.w;
            ring[(j + 8) % 9] = v;

            // Horizontal 9-sum over cols [cout .. cout+3]+[-4..+4]
            const float s3 = vs.w;                 // suffixes (exact adds)
            const float s2 = vs.z + s3;
            const float s1 = vs.y + s2;
            const float S  = vs.x + s1;            // full 4-sum
            const float p2 = vs.x + vs.y;          // prefixes
            const float p3 = p2 + vs.z;

            const float T  = __shfl_down(S, 1);    // fullsum of lane+1
            const float q1 = __shfl_down(vs.x, 2); // prefixes of lane+2
            const float q2 = __shfl_down(p2, 2);
            const float q3 = __shfl_down(p3, 2);
            const float q4 = __shfl_down(S, 2);

            f4 h;
            h.x = S  + T + q1;
            h.y = s1 + T + q2;
            h.z = s2 + T + q3;
            h.w = s3 + T + q4;
            if (stOK) __builtin_nontemporal_store(h, (f4*)po);
            po += W_IMG;

            const f4 old = ring[j];                // row leaving the window
            vs.x -= old.x; vs.y -= old.y; vs.z -= old.z; vs.w -= old.w;
        }
    }
}

extern "C" void kernel_launch(void* const* d_in, const int* in_sizes, int n_in,
                              void* d_out, int out_size, void* d_ws, size_t ws_size,
                              hipStream_t stream) {
    const float* x = (const float*)d_in[0];
    float* out = (float*)d_out;
    // 8 strips (2 blocks x 4 waves), 40 row segments, 24 images
    dim3 grid(2, 40, 24);
    box9_wave4<<<grid, 256, 0, stream>>>(x, out);
}

// Round 2
// 345.275 us; speedup vs baseline: 1.0234x; 1.0042x over previous
//
#include <hip/hip_runtime.h>

// BoxFilter (r=4): 9x9 clamped-window box SUM. Wave-streaming, float4/lane.
// Each wave: 62 active lanes x 4 cols = 248 input cols -> 240 output cols
// (1920 = 8 strips x 240). Streams SH=27 output rows (40 segments).
// Vertical 9-sum: register ring of float4 (static idx via 9-unrolled chunks).
// Horizontal 9-sum: per-lane prefix/suffix + 5 shuffles per 4 outputs.
//
// R2 change: LOOP-CARRIED prefetch. R1's same-block batch staging was legally
// re-interleaved by the machine scheduler (VGPR stayed 48, dur unchanged).
// Now st[j] is consumed and immediately re-loaded with chunk n+1's row j:
// the load and its use are separated by the chunk loop's BACK-EDGE, which the
// block-local scheduler cannot cross -> structurally guaranteed depth-9
// pipeline per wave. Chunk loop kept rolled (#pragma unroll 1) -- unrolling
// would merge blocks and reopen R1's failure. Last chunk peeled (no prefetch)
// to avoid 9 wasted row loads per wave.
// Hard-coded B=8,C=3,H=1080,W=1920,r=4.

#define W_IMG 1920
#define H_IMG 1080
#define SH 27          // output rows per segment (1080 = 40*27, 27%9==0)
#define R 4

typedef float f4 __attribute__((ext_vector_type(4)));

#define ROW_BODY(JJ, DO_PREFETCH)                                         \
    {                                                                     \
        const int row = row0 + chunk + (JJ) + R;   /* incoming row */     \
        f4 v = st[JJ];                                                    \
        if (DO_PREFETCH) {                         /* next chunk, slot JJ */\
            const int nrc = min(row + 9, H_IMG - 1);                      \
            st[JJ] = *(const f4*)(pcol + (long)nrc * W_IMG);              \
        }                                                                 \
        if (row >= H_IMG || !colOK) v = (f4){0.f, 0.f, 0.f, 0.f};         \
        vs += v;                                                          \
        ring[((JJ) + 8) % 9] = v;                                         \
                                                                          \
        /* Horizontal 9-sum over cols [cout .. cout+3]+[-4..+4] */        \
        const float s3 = vs.w;                 /* suffixes */             \
        const float s2 = vs.z + s3;                                       \
        const float s1 = vs.y + s2;                                       \
        const float S  = vs.x + s1;            /* full 4-sum */           \
        const float p2 = vs.x + vs.y;          /* prefixes */             \
        const float p3 = p2 + vs.z;                                       \
                                                                          \
        const float T  = __shfl_down(S, 1);    /* fullsum of lane+1 */    \
        const float q1 = __shfl_down(vs.x, 2); /* prefixes of lane+2 */   \
        const float q2 = __shfl_down(p2, 2);                              \
        const float q3 = __shfl_down(p3, 2);                              \
        const float q4 = __shfl_down(S, 2);                               \
                                                                          \
        f4 h;                                                             \
        h.x = S  + T + q1;                                                \
        h.y = s1 + T + q2;                                                \
        h.z = s2 + T + q3;                                                \
        h.w = s3 + T + q4;                                                \
        if (stOK) __builtin_nontemporal_store(h, (f4*)po);                \
        po += W_IMG;                                                      \
        vs -= ring[JJ];                        /* row leaving window */   \
    }

__global__ void box9_wave4(const float* __restrict__ x,
                           float* __restrict__ out) {
    const int lane  = threadIdx.x & 63;
    const int wv    = threadIdx.x >> 6;
    const int strip = blockIdx.x * 4 + wv;     // 0..7
    const int seg   = blockIdx.y;              // 0..39
    const int img   = blockIdx.z;              // 0..23
    const long base = (long)img * (H_IMG * W_IMG);

    // Lane l covers input cols cin_raw..cin_raw+3 (lane 0 = left halo).
    const int  cin_raw = strip * 240 - 4 + 4 * lane;
    const int  cin     = min(max(cin_raw, 0), W_IMG - 4);  // clamped (valid addr)
    const bool colOK   = (cin_raw >= 0) && (cin_raw + 3 < W_IMG);
    const int  cout    = strip * 240 + 4 * lane;
    const bool stOK    = (lane < 60);

    const int row0 = seg * SH;
    const float* pcol = x + base + cin;        // + row*W_IMG added per row
    float* po = out + base + (long)row0 * W_IMG + cout;

    f4 ring[9];
    f4 st[9];                                  // rotating prefetch buffer
    f4 vs = {0.f, 0.f, 0.f, 0.f};

    // Prologue: batch-issue 8 ring rows + 9 staged rows (17 loads in flight
    // before the first consume).
#pragma unroll
    for (int t = 0; t < 8; ++t) {
        const int rc = max(row0 - R + t, 0);          // lower clamp only
        ring[t] = *(const f4*)(pcol + (long)rc * W_IMG);
    }
#pragma unroll
    for (int j = 0; j < 9; ++j) {
        const int rc = min(row0 + j + R, H_IMG - 1);  // upper clamp only
        st[j] = *(const f4*)(pcol + (long)rc * W_IMG);
    }
#pragma unroll
    for (int t = 0; t < 8; ++t) {
        const int row = row0 - R + t;
        f4 v = ring[t];
        if (row < 0 || !colOK) v = (f4){0.f, 0.f, 0.f, 0.f};
        ring[t] = v;
        vs += v;
    }

    // Main: chunks 0..SH-18 with loop-carried prefetch; chunk loop MUST stay
    // rolled so the back-edge pins the prefetch loads a full chunk ahead.
#pragma unroll 1
    for (int chunk = 0; chunk < SH - 9; chunk += 9) {
#pragma unroll
        for (int j = 0; j < 9; ++j) ROW_BODY(j, true);
    }
    // Peeled last chunk: consume only, no prefetch (avoids 9 wasted loads).
    {
        const int chunk = SH - 9;
#pragma unroll
        for (int j = 0; j < 9; ++j) ROW_BODY(j, false);
    }
}

extern "C" void kernel_launch(void* const* d_in, const int* in_sizes, int n_in,
                              void* d_out, int out_size, void* d_ws, size_t ws_size,
                              hipStream_t stream) {
    const float* x = (const float*)d_in[0];
    float* out = (float*)d_out;
    // 8 strips (2 blocks x 4 waves), 40 row segments, 24 images
    dim3 grid(2, 40, 24);
    box9_wave4<<<grid, 256, 0, stream>>>(x, out);
}